// Round 3
// baseline (1969.158 us; speedup 1.0000x reference)
//
#include <hip/hip_runtime.h>
#include <math.h>

#define NB 4
#define NN 4096
#define NS 32
#define NTOT (NB*NN*NS)   // 524288

__device__ __forceinline__ float lrelu(float x){ return x > 0.0f ? x : 0.2f*x; }

// ---------------- K1: ball query (first NS indices within radius, ascending) ----------------
__global__ __launch_bounds__(256) void k_ballquery(const float* __restrict__ pts, int* __restrict__ idx) {
  __shared__ float sx[NN], sy[NN], sz[NN], sq[NN];
  const int b = blockIdx.x >> 7;          // 128 tiles per batch
  const int tile = blockIdx.x & 127;      // 32 n per tile
  const float* p = pts + b*3*NN;
  for (int i = threadIdx.x; i < NN; i += 256) {
    float x = p[i], y = p[NN+i], z = p[2*NN+i];
    sx[i]=x; sy[i]=y; sz[i]=z;
    // match reference: sq = ((x*x + y*y) + z*z), no contraction
    sq[i] = __fadd_rn(__fadd_rn(__fmul_rn(x,x), __fmul_rn(y,y)), __fmul_rn(z,z));
  }
  __syncthreads();
  const int wave = threadIdx.x >> 6;
  const int lane = threadIdx.x & 63;
  for (int w = 0; w < 8; ++w) {
    const int n = tile*32 + wave*8 + w;
    const float cx = sx[n], cy = sy[n], cz = sz[n], cq = sq[n];
    int* row = idx + (((b << 12) + n) << 5);
    int count = 0;
    int first = 0;
    for (int jb = 0; jb < NN; jb += 64) {
      const int j = jb + lane;
      // dot via ascending FMA chain (Eigen sgemm K=3 order)
      float dot = fmaf(sz[j], cz, fmaf(sy[j], cy, __fmul_rn(sx[j], cx)));
      // 2*dot is exact (power-of-two), so single-rounded subtract either way
      float r = __fsub_rn(__fadd_rn(cq, sq[j]), __fmul_rn(2.0f, dot));
      bool valid = !(r > 0.04f);
      unsigned long long m = __ballot(valid);
      if (count == 0 && m != 0ull) first = jb + (int)__builtin_ctzll(m);
      int pos = count + (int)__popcll(m & ((1ull << lane) - 1ull));
      if (valid && pos < NS) row[pos] = j;
      count += (int)__popcll(m);
      if (count >= NS) break;   // count is wave-uniform
    }
    for (int pp = count + lane; pp < NS; pp += 64) row[pp] = first;
  }
}

// ---------------- K2: layer0 stats (no store) ----------------
__global__ __launch_bounds__(256) void k_stats0(const float* __restrict__ pts, const int* __restrict__ idx,
    const float* __restrict__ w0, const float* __restrict__ b0, float* __restrict__ part) {
  float ls[32], lq[32];
  #pragma unroll
  for (int c=0;c<32;c++){ ls[c]=0.f; lq[c]=0.f; }
  const int base = blockIdx.x * 2048;
  for (int k=0;k<8;k++){
    const int t = base + k*256 + (int)threadIdx.x;
    const int b = t >> 17;
    const int n = (t >> 5) & (NN-1);
    const int j = idx[t];
    const float* p = pts + b*3*NN;
    const float cx = p[n], cy = p[NN+n], cz = p[2*NN+n];
    const float e3 = p[j]-cx, e4 = p[NN+j]-cy, e5 = p[2*NN+j]-cz;
    #pragma unroll
    for (int c=0;c<32;c++){
      float v = b0[c];
      v = fmaf(cx, w0[c*6+0], v);
      v = fmaf(cy, w0[c*6+1], v);
      v = fmaf(cz, w0[c*6+2], v);
      v = fmaf(e3, w0[c*6+3], v);
      v = fmaf(e4, w0[c*6+4], v);
      v = fmaf(e5, w0[c*6+5], v);
      ls[c] += v; lq[c] = fmaf(v,v,lq[c]);
    }
  }
  #pragma unroll
  for (int off=32; off>=1; off>>=1){
    #pragma unroll
    for (int c=0;c<32;c++){ ls[c] += __shfl_xor(ls[c], off); lq[c] += __shfl_xor(lq[c], off); }
  }
  const int lane = threadIdx.x & 63;
  const int cl = lane & 31;
  float vs=0.f, vq=0.f;
  #pragma unroll
  for (int c=0;c<32;c++) if (cl==c){ vs=ls[c]; vq=lq[c]; }
  float* dst = part + (blockIdx.x*4 + (threadIdx.x>>6))*64;
  if (lane < 32) { dst[cl]=vs; dst[32+cl]=vq; }
}

// ---------------- finalize: partials -> scale/shift ----------------
__global__ __launch_bounds__(256) void k_fin(const float* __restrict__ part, int E, int C,
    const float* __restrict__ g, const float* __restrict__ beta, float* __restrict__ bn) {
  __shared__ float red[512];
  const int c = threadIdx.x & (C-1);
  const int sl = (int)threadIdx.x / C;
  const int nsl = 256 / C;
  float s=0.f, qq=0.f;
  for (int i=sl; i<E; i+=nsl){ s += part[i*2*C + c]; qq += part[i*2*C + C + c]; }
  red[threadIdx.x] = s; red[256 + threadIdx.x] = qq;
  __syncthreads();
  if ((int)threadIdx.x < C) {
    float ts=0.f, tq=0.f;
    for (int k2=0;k2<nsl;k2++){ ts += red[k2*C + c]; tq += red[256 + k2*C + c]; }
    const float inv = 1.0f / (float)NTOT;   // 2^-19, exact
    float m = ts * inv;
    float var = fmaxf(tq*inv - m*m, 0.0f);
    float sc = g[c] / sqrtf(var + 1e-5f);
    bn[c] = sc;
    bn[C+c] = beta[c] - m*sc;
  }
}

// ---------------- K3: layer0 (recompute) + bn0 + lrelu + layer1, store x1, stats1 ----------------
__global__ __launch_bounds__(256) void k_layer01(const float* __restrict__ pts, const int* __restrict__ idx,
    const float* __restrict__ w0, const float* __restrict__ b0, const float* __restrict__ bn0,
    const float* __restrict__ w1, const float* __restrict__ b1,
    float* __restrict__ x1, float* __restrict__ part) {
  float ls[32], lq[32];
  #pragma unroll
  for (int c=0;c<32;c++){ ls[c]=0.f; lq[c]=0.f; }
  const int base = blockIdx.x * 1024;
  for (int k=0;k<4;k++){
    const int t = base + k*256 + (int)threadIdx.x;
    const int b = t >> 17;
    const int n = (t >> 5) & (NN-1);
    const int j = idx[t];
    const float* p = pts + b*3*NN;
    const float cx = p[n], cy = p[NN+n], cz = p[2*NN+n];
    const float e3 = p[j]-cx, e4 = p[NN+j]-cy, e5 = p[2*NN+j]-cz;
    float h0[32];
    #pragma unroll
    for (int c=0;c<32;c++){
      float v = b0[c];
      v = fmaf(cx, w0[c*6+0], v);
      v = fmaf(cy, w0[c*6+1], v);
      v = fmaf(cz, w0[c*6+2], v);
      v = fmaf(e3, w0[c*6+3], v);
      v = fmaf(e4, w0[c*6+4], v);
      v = fmaf(e5, w0[c*6+5], v);
      h0[c] = lrelu(fmaf(v, bn0[c], bn0[32+c]));
    }
    float acc[32];
    #pragma unroll
    for (int o=0;o<32;o++){
      float a = b1[o];
      #pragma unroll
      for (int c=0;c<32;c++) a = fmaf(h0[c], w1[o*32+c], a);
      acc[o] = a;
      ls[o] += a; lq[o] = fmaf(a,a,lq[o]);
    }
    float4* dst4 = (float4*)(x1 + (size_t)t*32);
    #pragma unroll
    for (int u=0;u<8;u++) dst4[u] = make_float4(acc[4*u], acc[4*u+1], acc[4*u+2], acc[4*u+3]);
  }
  #pragma unroll
  for (int off=32; off>=1; off>>=1){
    #pragma unroll
    for (int c=0;c<32;c++){ ls[c] += __shfl_xor(ls[c], off); lq[c] += __shfl_xor(lq[c], off); }
  }
  const int lane = threadIdx.x & 63;
  const int cl = lane & 31;
  float vs=0.f, vq=0.f;
  #pragma unroll
  for (int c=0;c<32;c++) if (cl==c){ vs=ls[c]; vq=lq[c]; }
  float* dst = part + (blockIdx.x*4 + (threadIdx.x>>6))*64;
  if (lane < 32) { dst[cl]=vs; dst[32+cl]=vq; }
}

// ---------------- K4: bn1 + lrelu + layer2 stats (no store) ----------------
// 4 waves/block: wave = (row-group g, channel-half q). Each row visited by exactly
// 2 waves (the two channel halves); row-groups are disjoint -> x1 read 2x (was 4x).
__global__ __launch_bounds__(256) void k_stats2(const float* __restrict__ x1, const float* __restrict__ bn1,
    const float* __restrict__ w2, const float* __restrict__ b2, float* __restrict__ part) {
  const int wave = threadIdx.x >> 6;
  const int lane = threadIdx.x & 63;
  const int q  = (wave & 1) * 32;         // channel half (wave-uniform -> w2 via s_load)
  const int g  = wave >> 1;               // row group
  float ls[32], lq[32];
  #pragma unroll
  for (int i=0;i<32;i++){ ls[i]=0.f; lq[i]=0.f; }
  const int base = blockIdx.x * 1024;
  for (int k=0;k<8;k++){
    const int t = base + k*128 + g*64 + lane;
    const float4* r4 = (const float4*)(x1 + (size_t)t*32);
    float hv[32];
    #pragma unroll
    for (int u=0;u<8;u++){
      float4 v4 = r4[u];
      hv[4*u+0] = lrelu(fmaf(v4.x, bn1[4*u+0], bn1[32+4*u+0]));
      hv[4*u+1] = lrelu(fmaf(v4.y, bn1[4*u+1], bn1[32+4*u+1]));
      hv[4*u+2] = lrelu(fmaf(v4.z, bn1[4*u+2], bn1[32+4*u+2]));
      hv[4*u+3] = lrelu(fmaf(v4.w, bn1[4*u+3], bn1[32+4*u+3]));
    }
    #pragma unroll
    for (int i=0;i<32;i++){
      float a = b2[q+i];
      #pragma unroll
      for (int c=0;c<32;c++) a = fmaf(hv[c], w2[(q+i)*32+c], a);
      ls[i] += a; lq[i] = fmaf(a,a,lq[i]);
    }
  }
  #pragma unroll
  for (int off=32; off>=1; off>>=1){
    #pragma unroll
    for (int i=0;i<32;i++){ ls[i] += __shfl_xor(ls[i], off); lq[i] += __shfl_xor(lq[i], off); }
  }
  const int cl = lane & 31;
  float vs=0.f, vq=0.f;
  #pragma unroll
  for (int i=0;i<32;i++) if (cl==i){ vs=ls[i]; vq=lq[i]; }
  float* dst = part + (blockIdx.x*2 + g)*128;   // [1024][128]: 64 sums + 64 sumsq
  if (lane < 32){ dst[q+cl] = vs; dst[64+q+cl] = vq; }
}

// ---------------- K5: bn1+lrelu+layer2 (recompute)+bn2+lrelu, max over s, write (B,64,N) ----------------
// lane = (p, sidx): owns point p's rows sidx and sidx+16 -> each lane reads its own
// contiguous 128B rows with immediate full reuse (fixes the 4x overfetch).
// 16 points per block -> 1024 blocks total.
__global__ __launch_bounds__(256,3) void k_final(const float* __restrict__ x1, const float* __restrict__ bn1,
    const float* __restrict__ w2, const float* __restrict__ b2, const float* __restrict__ bn2,
    float* __restrict__ out) {
  __shared__ float lout[64][17];          // [channel][point-in-block], 16 cols + pad
  const int wave = threadIdx.x >> 6;
  const int lane = threadIdx.x & 63;
  const int p    = lane >> 4;             // point within wave (0..3)
  const int sidx = lane & 15;             // sample slot (0..15)
  const int b     = blockIdx.x >> 8;      // 256 blocks per batch
  const int nbase = (blockIdx.x & 255) << 4;
  const int n     = nbase + wave*4 + p;
  const size_t trow = ((size_t)((b << 12) + n)) << 5;   // first row index for this point
  float mx[64];
  #pragma unroll
  for (int i=0;i<64;i++) mx[i] = -3.0e38f;
  #pragma unroll 1
  for (int rr=0; rr<2; ++rr){
    const int s = sidx + rr*16;
    const float4* r4 = (const float4*)(x1 + (trow + (size_t)s)*32);
    float hv[32];
    #pragma unroll
    for (int u=0;u<8;u++){
      float4 v4 = r4[u];
      hv[4*u+0] = lrelu(fmaf(v4.x, bn1[4*u+0], bn1[32+4*u+0]));
      hv[4*u+1] = lrelu(fmaf(v4.y, bn1[4*u+1], bn1[32+4*u+1]));
      hv[4*u+2] = lrelu(fmaf(v4.z, bn1[4*u+2], bn1[32+4*u+2]));
      hv[4*u+3] = lrelu(fmaf(v4.w, bn1[4*u+3], bn1[32+4*u+3]));
    }
    #pragma unroll
    for (int o=0;o<64;o++){
      float a = b2[o];
      #pragma unroll
      for (int c=0;c<32;c++) a = fmaf(hv[c], w2[o*32+c], a);
      float v = lrelu(fmaf(a, bn2[o], bn2[64+o]));
      mx[o] = fmaxf(mx[o], v);
    }
  }
  // max over the 16 lanes (s-slots) of each point
  #pragma unroll
  for (int m=8; m>=1; m>>=1){
    #pragma unroll
    for (int o=0;o<64;o++) mx[o] = fmaxf(mx[o], __shfl_xor(mx[o], m));
  }
  // transpose via LDS: lane writes 4 channels of its point
  const int col = wave*4 + p;
  #pragma unroll
  for (int k=0;k<4;k++) lout[4*sidx+k][col] = mx[4*sidx+k];
  __syncthreads();
  // coalesced 64B-row writes: out[b][ch][nbase..nbase+15]
  const int r  = threadIdx.x >> 2;
  const int c4 = (threadIdx.x & 3) << 2;
  float4 v;
  v.x = lout[r][c4]; v.y = lout[r][c4+1]; v.z = lout[r][c4+2]; v.w = lout[r][c4+3];
  *(float4*)(out + (((size_t)(b*64 + r)) << 12) + nbase + c4) = v;
}

extern "C" void kernel_launch(void* const* d_in, const int* in_sizes, int n_in,
                              void* d_out, int out_size, void* d_ws, size_t ws_size,
                              hipStream_t stream) {
  const float* pts = (const float*)d_in[0];
  const float* w0  = (const float*)d_in[1];
  const float* b0  = (const float*)d_in[2];
  const float* g0  = (const float*)d_in[3];
  const float* be0 = (const float*)d_in[4];
  const float* w1  = (const float*)d_in[5];
  const float* b1  = (const float*)d_in[6];
  const float* g1  = (const float*)d_in[7];
  const float* be1 = (const float*)d_in[8];
  const float* w2  = (const float*)d_in[9];
  const float* b2  = (const float*)d_in[10];
  const float* g2  = (const float*)d_in[11];
  const float* be2 = (const float*)d_in[12];
  float* out = (float*)d_out;

  char* ws = (char*)d_ws;
  int*   idx = (int*)  (ws + 0);           // 2 MB
  float* x1  = (float*)(ws + 2097152);     // 67.1 MB -> ends 69206016
  float* p0  = (float*)(ws + 69206016);    // 1024*64*4 = 256KB
  float* p1  = (float*)(ws + 69468160);    // 2048*64*4 = 512KB -> ends 69992448
  float* p2  = (float*)(ws + 69206016);    // 1024*128*4 = 512KB, reuses p0+p1 space (dead by then)
  float* bn0 = (float*)(ws + 69992448);
  float* bn1 = (float*)(ws + 69993472);
  float* bn2 = (float*)(ws + 69994496);

  k_ballquery<<<512,  256, 0, stream>>>(pts, idx);
  k_stats0  <<<256,  256, 0, stream>>>(pts, idx, w0, b0, p0);
  k_fin     <<<1,    256, 0, stream>>>(p0, 1024, 32, g0, be0, bn0);
  k_layer01 <<<512,  256, 0, stream>>>(pts, idx, w0, b0, bn0, w1, b1, x1, p1);
  k_fin     <<<1,    256, 0, stream>>>(p1, 2048, 32, g1, be1, bn1);
  k_stats2  <<<512,  256, 0, stream>>>(x1, bn1, w2, b2, p2);
  k_fin     <<<1,    256, 0, stream>>>(p2, 1024, 64, g2, be2, bn2);
  k_final   <<<1024, 256, 0, stream>>>(x1, bn1, w2, b2, bn2, out);
}

// Round 4
// 384.191 us; speedup vs baseline: 5.1255x; 5.1255x over previous
//
#include <hip/hip_runtime.h>
#include <math.h>

#define NB 4
#define NN 4096
#define NS 32
#define NTOT (NB*NN*NS)   // 524288

__device__ __forceinline__ float lrelu(float x){ return x > 0.0f ? x : 0.2f*x; }
__device__ __forceinline__ int symoff(int i, int j){
  return (i<=j) ? (i*(11-i))/2 + j : (j*(11-j))/2 + i;   // 6x6 sym packed index
}

// ---------------- K1: ball query (first NS indices within radius, ascending) ----------------
__global__ __launch_bounds__(256) void k_ballquery(const float* __restrict__ pts, int* __restrict__ idx) {
  __shared__ float sx[NN], sy[NN], sz[NN], sq[NN];
  const int b = blockIdx.x >> 7;
  const int tile = blockIdx.x & 127;
  const float* p = pts + b*3*NN;
  for (int i = threadIdx.x; i < NN; i += 256) {
    float x = p[i], y = p[NN+i], z = p[2*NN+i];
    sx[i]=x; sy[i]=y; sz[i]=z;
    sq[i] = __fadd_rn(__fadd_rn(__fmul_rn(x,x), __fmul_rn(y,y)), __fmul_rn(z,z));
  }
  __syncthreads();
  const int wave = threadIdx.x >> 6;
  const int lane = threadIdx.x & 63;
  for (int w = 0; w < 8; ++w) {
    const int n = tile*32 + wave*8 + w;
    const float cx = sx[n], cy = sy[n], cz = sz[n], cq = sq[n];
    int* row = idx + (((b << 12) + n) << 5);
    int count = 0;
    int first = 0;
    for (int jb = 0; jb < NN; jb += 64) {
      const int j = jb + lane;
      float dot = fmaf(sz[j], cz, fmaf(sy[j], cy, __fmul_rn(sx[j], cx)));
      float r = __fsub_rn(__fadd_rn(cq, sq[j]), __fmul_rn(2.0f, dot));
      bool valid = !(r > 0.04f);
      unsigned long long m = __ballot(valid);
      if (count == 0 && m != 0ull) first = jb + (int)__builtin_ctzll(m);
      int pos = count + (int)__popcll(m & ((1ull << lane) - 1ull));
      if (valid && pos < NS) row[pos] = j;
      count += (int)__popcll(m);
      if (count >= NS) break;
    }
    for (int pp = count + lane; pp < NS; pp += 64) row[pp] = first;
  }
}

// ---------------- K2: edge-feature Gram stats: S_e[6], M_e[21] (27 acc/lane) ----------------
__global__ __launch_bounds__(256) void k_stats0g(const float* __restrict__ pts, const int* __restrict__ idx,
                                                 float* __restrict__ part0) {
  float S[6], M[21];
  #pragma unroll
  for (int i=0;i<6;i++) S[i]=0.f;
  #pragma unroll
  for (int i=0;i<21;i++) M[i]=0.f;
  const int base = blockIdx.x * 1024;
  for (int k=0;k<4;k++){
    const int t = base + k*256 + (int)threadIdx.x;
    const int b = t >> 17;
    const int n = (t >> 5) & (NN-1);
    const int j = idx[t];
    const float* p = pts + b*3*NN;
    float v[6];
    v[0]=p[n]; v[1]=p[NN+n]; v[2]=p[2*NN+n];
    v[3]=p[j]-v[0]; v[4]=p[NN+j]-v[1]; v[5]=p[2*NN+j]-v[2];
    #pragma unroll
    for (int i=0;i<6;i++) S[i] += v[i];
    int c=0;
    #pragma unroll
    for (int i=0;i<6;i++)
      #pragma unroll
      for (int jj=i;jj<6;jj++){ M[c] = fmaf(v[i], v[jj], M[c]); c++; }
  }
  // wave reduce
  #pragma unroll
  for (int off=32; off>=1; off>>=1){
    #pragma unroll
    for (int i=0;i<6;i++)  S[i] += __shfl_xor(S[i], off);
    #pragma unroll
    for (int i=0;i<21;i++) M[i] += __shfl_xor(M[i], off);
  }
  __shared__ float red[4][27];
  const int wave = threadIdx.x >> 6, lane = threadIdx.x & 63;
  if (lane == 0){
    #pragma unroll
    for (int i=0;i<6;i++)  red[wave][i]   = S[i];
    #pragma unroll
    for (int i=0;i<21;i++) red[wave][6+i] = M[i];
  }
  __syncthreads();
  if (threadIdx.x < 27){
    float a = red[0][threadIdx.x]+red[1][threadIdx.x]+red[2][threadIdx.x]+red[3][threadIdx.x];
    part0[blockIdx.x*32 + threadIdx.x] = a;
  }
}

// ---------------- finalize bn0 from Gram ----------------
__global__ __launch_bounds__(256) void k_fin0g(const float* __restrict__ part0,
    const float* __restrict__ w0, const float* __restrict__ b0,
    const float* __restrict__ g0, const float* __restrict__ be0, float* __restrict__ bn0) {
  __shared__ float SM[27];
  if (threadIdx.x < 27){
    float s=0.f;
    for (int b=0;b<512;b++) s += part0[b*32 + threadIdx.x];
    SM[threadIdx.x] = s;
  }
  __syncthreads();
  if (threadIdx.x < 32){
    const int cch = threadIdx.x;
    float w[6];
    #pragma unroll
    for (int i=0;i<6;i++) w[i] = w0[cch*6+i];
    float dot=0.f;
    #pragma unroll
    for (int i=0;i<6;i++) dot = fmaf(w[i], SM[i], dot);
    float qd=0.f;
    #pragma unroll
    for (int i=0;i<6;i++){
      float ti=0.f;
      #pragma unroll
      for (int j=0;j<6;j++) ti = fmaf(w[j], SM[6+symoff(i,j)], ti);
      qd = fmaf(w[i], ti, qd);
    }
    const float NT = (float)NTOT;
    const float bb = b0[cch];
    float s1 = dot + NT*bb;
    float s2 = qd + 2.f*bb*dot + NT*bb*bb;
    const float inv = 1.0f / NT;
    float mean = s1 * inv;
    float var  = fmaxf(s2*inv - mean*mean, 0.0f);
    float sc = g0[cch] / sqrtf(var + 1e-5f);
    bn0[cch] = sc;
    bn0[32+cch] = be0[cch] - mean*sc;
  }
}

// ---------------- generic finalize: partials [E][2C] -> scale/shift ----------------
__global__ __launch_bounds__(256) void k_fin(const float* __restrict__ part, int E, int C,
    const float* __restrict__ g, const float* __restrict__ beta, float* __restrict__ bn) {
  __shared__ float red[512];
  const int c = threadIdx.x & (C-1);
  const int sl = (int)threadIdx.x / C;
  const int nsl = 256 / C;
  float s=0.f, qq=0.f;
  for (int i=sl; i<E; i+=nsl){ s += part[i*2*C + c]; qq += part[i*2*C + C + c]; }
  red[threadIdx.x] = s; red[256 + threadIdx.x] = qq;
  __syncthreads();
  if ((int)threadIdx.x < C) {
    float ts=0.f, tq=0.f;
    for (int k2=0;k2<nsl;k2++){ ts += red[k2*C + c]; tq += red[256 + k2*C + c]; }
    const float inv = 1.0f / (float)NTOT;
    float m = ts * inv;
    float var = fmaxf(tq*inv - m*m, 0.0f);
    float sc = g[c] / sqrtf(var + 1e-5f);
    bn[c] = sc;
    bn[C+c] = beta[c] - m*sc;
  }
}

// ---------------- K3: layer0 (recompute) + bn0 + lrelu + layer1 -> x1 (no stats) ----------------
__global__ __launch_bounds__(256) void k_layer01(const float* __restrict__ pts, const int* __restrict__ idx,
    const float* __restrict__ w0, const float* __restrict__ b0, const float* __restrict__ bn0,
    const float* __restrict__ w1, const float* __restrict__ b1, float* __restrict__ x1) {
  const int base = blockIdx.x * 512;
  for (int k=0;k<2;k++){
    const int t = base + k*256 + (int)threadIdx.x;
    const int b = t >> 17;
    const int n = (t >> 5) & (NN-1);
    const int j = idx[t];
    const float* p = pts + b*3*NN;
    const float cx = p[n], cy = p[NN+n], cz = p[2*NN+n];
    const float e3 = p[j]-cx, e4 = p[NN+j]-cy, e5 = p[2*NN+j]-cz;
    float h0[32];
    #pragma unroll
    for (int c=0;c<32;c++){
      float v = b0[c];
      v = fmaf(cx, w0[c*6+0], v);
      v = fmaf(cy, w0[c*6+1], v);
      v = fmaf(cz, w0[c*6+2], v);
      v = fmaf(e3, w0[c*6+3], v);
      v = fmaf(e4, w0[c*6+4], v);
      v = fmaf(e5, w0[c*6+5], v);
      h0[c] = lrelu(fmaf(v, bn0[c], bn0[32+c]));
    }
    float4* dst4 = (float4*)(x1 + (size_t)t*32);
    #pragma unroll
    for (int og=0; og<8; ++og){
      float a0=b1[4*og+0], a1=b1[4*og+1], a2=b1[4*og+2], a3=b1[4*og+3];
      #pragma unroll
      for (int c=0;c<32;c++){
        a0 = fmaf(h0[c], w1[(4*og+0)*32+c], a0);
        a1 = fmaf(h0[c], w1[(4*og+1)*32+c], a1);
        a2 = fmaf(h0[c], w1[(4*og+2)*32+c], a2);
        a3 = fmaf(h0[c], w1[(4*og+3)*32+c], a3);
      }
      dst4[og] = make_float4(a0,a1,a2,a3);
    }
  }
}

// ---------------- K4: layer1 stats = column sums of x1 (8 acc/thread) ----------------
__global__ __launch_bounds__(256) void k_stats1(const float* __restrict__ x1, float* __restrict__ part) {
  const int tid = threadIdx.x;
  const int rlo = tid >> 3, cq = tid & 7;
  float s[4]={0,0,0,0}, q[4]={0,0,0,0};
  const int rbase = blockIdx.x * 512;
  for (int k=0;k<16;k++){
    const int r = rbase + k*32 + rlo;
    const float4 v = *(const float4*)(x1 + (size_t)r*32 + cq*4);
    s[0]+=v.x; q[0]=fmaf(v.x,v.x,q[0]);
    s[1]+=v.y; q[1]=fmaf(v.y,v.y,q[1]);
    s[2]+=v.z; q[2]=fmaf(v.z,v.z,q[2]);
    s[3]+=v.w; q[3]=fmaf(v.w,v.w,q[3]);
  }
  __shared__ float red[2048];
  #pragma unroll
  for (int i=0;i<4;i++){ red[tid*4+i] = s[i]; red[1024 + tid*4+i] = q[i]; }
  __syncthreads();
  if (tid < 32){
    float ts=0.f, tq=0.f;
    for (int m=0;m<32;m++){
      const int a = (m*8 + (tid>>2))*4 + (tid&3);
      ts += red[a]; tq += red[1024+a];
    }
    part[blockIdx.x*64 + tid] = ts;
    part[blockIdx.x*64 + 32 + tid] = tq;
  }
}

// ---------------- shared staging for K5/K6: 8 points x 32 rows of h1 into LDS ----------------
#define PSTRIDE 1160   // floats per point region (32 rows * 36) + 8 stagger
__device__ __forceinline__ void stage_h1(const float* __restrict__ x1, const float* __restrict__ bn1,
                                         float* __restrict__ h, int t0, int tid) {
  const int rlo = tid >> 3, cq = tid & 7;
  const float sc0 = bn1[cq*4+0], sc1 = bn1[cq*4+1], sc2 = bn1[cq*4+2], sc3 = bn1[cq*4+3];
  const float sh0 = bn1[32+cq*4+0], sh1 = bn1[32+cq*4+1], sh2 = bn1[32+cq*4+2], sh3 = bn1[32+cq*4+3];
  for (int k=0;k<8;k++){
    const int r = k*32 + rlo;
    const float4 v = *(const float4*)(x1 + (size_t)(t0 + r)*32 + cq*4);
    float* d = h + (r>>5)*PSTRIDE + (r&31)*36 + cq*4;
    d[0] = lrelu(fmaf(v.x, sc0, sh0));
    d[1] = lrelu(fmaf(v.y, sc1, sh1));
    d[2] = lrelu(fmaf(v.z, sc2, sh2));
    d[3] = lrelu(fmaf(v.w, sc3, sh3));
  }
}

// ---------------- K5: layer2 stats. thread = (point p, channel pair o0,o1) ----------------
__global__ __launch_bounds__(256) void k_stats2(const float* __restrict__ x1, const float* __restrict__ bn1,
    const float* __restrict__ w2, const float* __restrict__ b2, float* __restrict__ part) {
  __shared__ float h[8*PSTRIDE];
  const int tid = threadIdx.x;
  const int t0 = blockIdx.x * 256;
  stage_h1(x1, bn1, h, t0, tid);
  __syncthreads();
  const int q = tid & 31, p = tid >> 5;
  const int o0 = 2*q, o1 = 2*q+1;
  float wa[32], wb[32];
  #pragma unroll
  for (int i=0;i<8;i++){
    const float4 A = *(const float4*)(w2 + o0*32 + i*4);
    wa[4*i+0]=A.x; wa[4*i+1]=A.y; wa[4*i+2]=A.z; wa[4*i+3]=A.w;
    const float4 B = *(const float4*)(w2 + o1*32 + i*4);
    wb[4*i+0]=B.x; wb[4*i+1]=B.y; wb[4*i+2]=B.z; wb[4*i+3]=B.w;
  }
  const float bb0 = b2[o0], bb1 = b2[o1];
  float s0=0.f, s1=0.f, q0=0.f, q1=0.f;
  const float* hp = h + p*PSTRIDE;
  for (int s=0;s<32;s++){
    const float* row = hp + s*36;
    float a0=bb0, a1=bb1;
    #pragma unroll
    for (int i=0;i<8;i++){
      const float4 hv = *(const float4*)(row + 4*i);
      a0 = fmaf(hv.x, wa[4*i+0], a0); a0 = fmaf(hv.y, wa[4*i+1], a0);
      a0 = fmaf(hv.z, wa[4*i+2], a0); a0 = fmaf(hv.w, wa[4*i+3], a0);
      a1 = fmaf(hv.x, wb[4*i+0], a1); a1 = fmaf(hv.y, wb[4*i+1], a1);
      a1 = fmaf(hv.z, wb[4*i+2], a1); a1 = fmaf(hv.w, wb[4*i+3], a1);
    }
    s0 += a0; q0 = fmaf(a0,a0,q0);
    s1 += a1; q1 = fmaf(a1,a1,q1);
  }
  __syncthreads();
  h[p*64+o0] = s0; h[p*64+o1] = s1;
  h[512 + p*64+o0] = q0; h[512 + p*64+o1] = q1;
  __syncthreads();
  if (tid < 128){
    const int o = tid & 63, half = tid >> 6;
    float acc = 0.f;
    #pragma unroll
    for (int pp=0;pp<8;pp++) acc += h[half*512 + pp*64 + o];
    part[blockIdx.x*128 + half*64 + o] = acc;
  }
}

// ---------------- K6: layer2 max (pre-bn2, monotone) + bn2 + lrelu + transposed write ----------------
__global__ __launch_bounds__(256) void k_final2(const float* __restrict__ x1, const float* __restrict__ bn1,
    const float* __restrict__ w2, const float* __restrict__ b2, const float* __restrict__ bn2,
    float* __restrict__ out) {
  __shared__ float h[8*PSTRIDE];
  const int tid = threadIdx.x;
  const int t0 = blockIdx.x * 256;
  stage_h1(x1, bn1, h, t0, tid);
  __syncthreads();
  const int q = tid & 31, p = tid >> 5;
  const int o0 = 2*q, o1 = 2*q+1;
  float wa[32], wb[32];
  #pragma unroll
  for (int i=0;i<8;i++){
    const float4 A = *(const float4*)(w2 + o0*32 + i*4);
    wa[4*i+0]=A.x; wa[4*i+1]=A.y; wa[4*i+2]=A.z; wa[4*i+3]=A.w;
    const float4 B = *(const float4*)(w2 + o1*32 + i*4);
    wb[4*i+0]=B.x; wb[4*i+1]=B.y; wb[4*i+2]=B.z; wb[4*i+3]=B.w;
  }
  const float bb0 = b2[o0], bb1 = b2[o1];
  float m0 = -3.0e38f, m1 = -3.0e38f;
  const float* hp = h + p*PSTRIDE;
  for (int s=0;s<32;s++){
    const float* row = hp + s*36;
    float a0=bb0, a1=bb1;
    #pragma unroll
    for (int i=0;i<8;i++){
      const float4 hv = *(const float4*)(row + 4*i);
      a0 = fmaf(hv.x, wa[4*i+0], a0); a0 = fmaf(hv.y, wa[4*i+1], a0);
      a0 = fmaf(hv.z, wa[4*i+2], a0); a0 = fmaf(hv.w, wa[4*i+3], a0);
      a1 = fmaf(hv.x, wb[4*i+0], a1); a1 = fmaf(hv.y, wb[4*i+1], a1);
      a1 = fmaf(hv.z, wb[4*i+2], a1); a1 = fmaf(hv.w, wb[4*i+3], a1);
    }
    m0 = fmaxf(m0, a0); m1 = fmaxf(m1, a1);
  }
  const float v0 = lrelu(fmaf(m0, bn2[o0], bn2[64+o0]));
  const float v1 = lrelu(fmaf(m1, bn2[o1], bn2[64+o1]));
  __syncthreads();
  h[p*65 + o0] = v0; h[p*65 + o1] = v1;   // res[8][65]
  __syncthreads();
  if (tid < 128){
    const int o = tid >> 1, pr = tid & 1;
    float4 v;
    v.x = h[(pr*4+0)*65 + o];
    v.y = h[(pr*4+1)*65 + o];
    v.z = h[(pr*4+2)*65 + o];
    v.w = h[(pr*4+3)*65 + o];
    const int np = blockIdx.x * 8;
    const int b = np >> 12, n0 = np & (NN-1);
    *(float4*)(out + (size_t)(b*64 + o)*NN + n0 + pr*4) = v;
  }
}

extern "C" void kernel_launch(void* const* d_in, const int* in_sizes, int n_in,
                              void* d_out, int out_size, void* d_ws, size_t ws_size,
                              hipStream_t stream) {
  const float* pts = (const float*)d_in[0];
  const float* w0  = (const float*)d_in[1];
  const float* b0  = (const float*)d_in[2];
  const float* g0  = (const float*)d_in[3];
  const float* be0 = (const float*)d_in[4];
  const float* w1  = (const float*)d_in[5];
  const float* b1  = (const float*)d_in[6];
  const float* g1  = (const float*)d_in[7];
  const float* be1 = (const float*)d_in[8];
  const float* w2  = (const float*)d_in[9];
  const float* b2  = (const float*)d_in[10];
  const float* g2  = (const float*)d_in[11];
  const float* be2 = (const float*)d_in[12];
  float* out = (float*)d_out;

  char* ws = (char*)d_ws;
  int*   idx   = (int*)  (ws + 0);          // 2 MB (dead after k_layer01)
  float* part2 = (float*)(ws + 0);          // 2048*128*4 = 1 MB, overlays dead idx
  float* x1    = (float*)(ws + 2097152);    // 67.1 MB -> 69206016
  float* part0 = (float*)(ws + 69206016);   // 512*32*4 = 64 KB
  float* part1 = (float*)(ws + 69271552);   // 1024*64*4 = 256 KB
  float* bn0   = (float*)(ws + 69533696);
  float* bn1   = (float*)(ws + 69533952);
  float* bn2   = (float*)(ws + 69534208);   // end ~69.53 MB (< previous 70.26 MB footprint)

  k_ballquery<<<512,  256, 0, stream>>>(pts, idx);
  k_stats0g <<<512,  256, 0, stream>>>(pts, idx, part0);
  k_fin0g   <<<1,    256, 0, stream>>>(part0, w0, b0, g0, be0, bn0);
  k_layer01 <<<1024, 256, 0, stream>>>(pts, idx, w0, b0, bn0, w1, b1, x1);
  k_stats1  <<<1024, 256, 0, stream>>>(x1, part1);
  k_fin     <<<1,    256, 0, stream>>>(part1, 1024, 32, g1, be1, bn1);
  k_stats2  <<<2048, 256, 0, stream>>>(x1, bn1, w2, b2, part2);
  k_fin     <<<1,    256, 0, stream>>>(part2, 2048, 64, g2, be2, bn2);
  k_final2  <<<2048, 256, 0, stream>>>(x1, bn1, w2, b2, bn2, out);
}

// Round 5
// 216.997 us; speedup vs baseline: 9.0746x; 1.7705x over previous
//
#include <hip/hip_runtime.h>
#include <math.h>

#define NB 4
#define NN 4096
#define NS 32
#define NTOT (NB*NN*NS)   // 524288
#define FXSCALE 16777216.0   // 2^24 fixed-point scale for deterministic i64 atomics

__device__ __forceinline__ float lrelu(float x){ return x > 0.0f ? x : 0.2f*x; }
__device__ __forceinline__ int symoff(int i, int j){
  return (i<=j) ? (i*(11-i))/2 + j : (j*(11-j))/2 + i;   // 6x6 sym packed index
}
__device__ __forceinline__ void atomic_fx(long long* p, float v){
  long long q = llrint((double)v * FXSCALE);            // double: exact for |v|<2^29
  atomicAdd((unsigned long long*)p, (unsigned long long)q);
}
__device__ __forceinline__ float fx2f(long long q){ return (float)((double)q * (1.0/FXSCALE)); }

// ---------------- K1: ball query (first NS indices within radius, ascending) ----------------
__global__ __launch_bounds__(256) void k_ballquery(const float* __restrict__ pts, int* __restrict__ idx) {
  __shared__ float sx[NN], sy[NN], sz[NN], sq[NN];
  const int b = blockIdx.x >> 7;
  const int tile = blockIdx.x & 127;
  const float* p = pts + b*3*NN;
  for (int i = threadIdx.x; i < NN; i += 256) {
    float x = p[i], y = p[NN+i], z = p[2*NN+i];
    sx[i]=x; sy[i]=y; sz[i]=z;
    sq[i] = __fadd_rn(__fadd_rn(__fmul_rn(x,x), __fmul_rn(y,y)), __fmul_rn(z,z));
  }
  __syncthreads();
  const int wave = threadIdx.x >> 6;
  const int lane = threadIdx.x & 63;
  for (int w = 0; w < 8; ++w) {
    const int n = tile*32 + wave*8 + w;
    const float cx = sx[n], cy = sy[n], cz = sz[n], cq = sq[n];
    int* row = idx + (((b << 12) + n) << 5);
    int count = 0;
    int first = 0;
    for (int jb = 0; jb < NN; jb += 64) {
      const int j = jb + lane;
      float dot = fmaf(sz[j], cz, fmaf(sy[j], cy, __fmul_rn(sx[j], cx)));
      float r = __fsub_rn(__fadd_rn(cq, sq[j]), __fmul_rn(2.0f, dot));
      bool valid = !(r > 0.04f);
      unsigned long long m = __ballot(valid);
      if (count == 0 && m != 0ull) first = jb + (int)__builtin_ctzll(m);
      int pos = count + (int)__popcll(m & ((1ull << lane) - 1ull));
      if (valid && pos < NS) row[pos] = j;
      count += (int)__popcll(m);
      if (count >= NS) break;
    }
    for (int pp = count + lane; pp < NS; pp += 64) row[pp] = first;
  }
}

// ---------------- K2: edge-feature Gram stats -> acc0[8][27] (i64 atomics) ----------------
__global__ __launch_bounds__(256) void k_stats0g(const float* __restrict__ pts, const int* __restrict__ idx,
                                                 long long* __restrict__ acc0) {
  float S[6], M[21];
  #pragma unroll
  for (int i=0;i<6;i++) S[i]=0.f;
  #pragma unroll
  for (int i=0;i<21;i++) M[i]=0.f;
  const int base = blockIdx.x * 1024;
  for (int k=0;k<4;k++){
    const int t = base + k*256 + (int)threadIdx.x;
    const int b = t >> 17;
    const int n = (t >> 5) & (NN-1);
    const int j = idx[t];
    const float* p = pts + b*3*NN;
    float v[6];
    v[0]=p[n]; v[1]=p[NN+n]; v[2]=p[2*NN+n];
    v[3]=p[j]-v[0]; v[4]=p[NN+j]-v[1]; v[5]=p[2*NN+j]-v[2];
    #pragma unroll
    for (int i=0;i<6;i++) S[i] += v[i];
    int c=0;
    #pragma unroll
    for (int i=0;i<6;i++)
      #pragma unroll
      for (int jj=i;jj<6;jj++){ M[c] = fmaf(v[i], v[jj], M[c]); c++; }
  }
  #pragma unroll
  for (int off=32; off>=1; off>>=1){
    #pragma unroll
    for (int i=0;i<6;i++)  S[i] += __shfl_xor(S[i], off);
    #pragma unroll
    for (int i=0;i<21;i++) M[i] += __shfl_xor(M[i], off);
  }
  __shared__ float red[4][27];
  const int wave = threadIdx.x >> 6, lane = threadIdx.x & 63;
  if (lane == 0){
    #pragma unroll
    for (int i=0;i<6;i++)  red[wave][i]   = S[i];
    #pragma unroll
    for (int i=0;i<21;i++) red[wave][6+i] = M[i];
  }
  __syncthreads();
  if (threadIdx.x < 27){
    float a = red[0][threadIdx.x]+red[1][threadIdx.x]+red[2][threadIdx.x]+red[3][threadIdx.x];
    atomic_fx(&acc0[(blockIdx.x & 7)*27 + threadIdx.x], a);
  }
}

// ---------------- finalize bn0 from Gram accumulators ----------------
__global__ __launch_bounds__(256) void k_fin0g(const long long* __restrict__ acc0,
    const float* __restrict__ w0, const float* __restrict__ b0,
    const float* __restrict__ g0, const float* __restrict__ be0, float* __restrict__ bn0) {
  __shared__ float SM[27];
  if (threadIdx.x < 27){
    long long s = 0;
    #pragma unroll
    for (int k=0;k<8;k++) s += acc0[k*27 + threadIdx.x];
    SM[threadIdx.x] = fx2f(s);
  }
  __syncthreads();
  if (threadIdx.x < 32){
    const int cch = threadIdx.x;
    float w[6];
    #pragma unroll
    for (int i=0;i<6;i++) w[i] = w0[cch*6+i];
    float dot=0.f;
    #pragma unroll
    for (int i=0;i<6;i++) dot = fmaf(w[i], SM[i], dot);
    float qd=0.f;
    #pragma unroll
    for (int i=0;i<6;i++){
      float ti=0.f;
      #pragma unroll
      for (int j=0;j<6;j++) ti = fmaf(w[j], SM[6+symoff(i,j)], ti);
      qd = fmaf(w[i], ti, qd);
    }
    const float NT = (float)NTOT;
    const float bb = b0[cch];
    float s1 = dot + NT*bb;
    float s2 = qd + 2.f*bb*dot + NT*bb*bb;
    const float inv = 1.0f / NT;
    float mean = s1 * inv;
    float var  = fmaxf(s2*inv - mean*mean, 0.0f);
    float sc = g0[cch] / sqrtf(var + 1e-5f);
    bn0[cch] = sc;
    bn0[32+cch] = be0[cch] - mean*sc;
  }
}

// ---------------- generic finalize: acc[NCOPY][2C] i64 -> scale/shift ----------------
__global__ __launch_bounds__(256) void k_fin(const long long* __restrict__ acc, int ncopy, int C,
    const float* __restrict__ g, const float* __restrict__ beta, float* __restrict__ bn) {
  if ((int)threadIdx.x < C) {
    const int c = threadIdx.x;
    long long ts = 0, tq = 0;
    for (int k=0;k<ncopy;k++){ ts += acc[k*2*C + c]; tq += acc[k*2*C + C + c]; }
    const float inv = 1.0f / (float)NTOT;
    float m = fx2f(ts) * inv;
    float var = fmaxf(fx2f(tq)*inv - m*m, 0.0f);
    float sc = g[c] / sqrtf(var + 1e-5f);
    bn[c] = sc;
    bn[C+c] = beta[c] - m*sc;
  }
}

// ---------------- K3: layer0 (recompute) + bn0 + lrelu + layer1 -> x1 ----------------
__global__ __launch_bounds__(256) void k_layer01(const float* __restrict__ pts, const int* __restrict__ idx,
    const float* __restrict__ w0, const float* __restrict__ b0, const float* __restrict__ bn0,
    const float* __restrict__ w1, const float* __restrict__ b1, float* __restrict__ x1) {
  const int base = blockIdx.x * 512;
  for (int k=0;k<2;k++){
    const int t = base + k*256 + (int)threadIdx.x;
    const int b = t >> 17;
    const int n = (t >> 5) & (NN-1);
    const int j = idx[t];
    const float* p = pts + b*3*NN;
    const float cx = p[n], cy = p[NN+n], cz = p[2*NN+n];
    const float e3 = p[j]-cx, e4 = p[NN+j]-cy, e5 = p[2*NN+j]-cz;
    float h0[32];
    #pragma unroll
    for (int c=0;c<32;c++){
      float v = b0[c];
      v = fmaf(cx, w0[c*6+0], v);
      v = fmaf(cy, w0[c*6+1], v);
      v = fmaf(cz, w0[c*6+2], v);
      v = fmaf(e3, w0[c*6+3], v);
      v = fmaf(e4, w0[c*6+4], v);
      v = fmaf(e5, w0[c*6+5], v);
      h0[c] = lrelu(fmaf(v, bn0[c], bn0[32+c]));
    }
    float4* dst4 = (float4*)(x1 + (size_t)t*32);
    #pragma unroll
    for (int og=0; og<8; ++og){
      float a0=b1[4*og+0], a1=b1[4*og+1], a2=b1[4*og+2], a3=b1[4*og+3];
      #pragma unroll
      for (int c=0;c<32;c++){
        a0 = fmaf(h0[c], w1[(4*og+0)*32+c], a0);
        a1 = fmaf(h0[c], w1[(4*og+1)*32+c], a1);
        a2 = fmaf(h0[c], w1[(4*og+2)*32+c], a2);
        a3 = fmaf(h0[c], w1[(4*og+3)*32+c], a3);
      }
      dst4[og] = make_float4(a0,a1,a2,a3);
    }
  }
}

// ---------------- K4: layer1 stats = column sums of x1 -> acc1[8][64] ----------------
__global__ __launch_bounds__(256) void k_stats1(const float* __restrict__ x1, long long* __restrict__ acc1) {
  const int tid = threadIdx.x;
  const int rlo = tid >> 3, cq = tid & 7;
  float s[4]={0,0,0,0}, q[4]={0,0,0,0};
  const int rbase = blockIdx.x * 512;
  for (int k=0;k<16;k++){
    const int r = rbase + k*32 + rlo;
    const float4 v = *(const float4*)(x1 + (size_t)r*32 + cq*4);
    s[0]+=v.x; q[0]=fmaf(v.x,v.x,q[0]);
    s[1]+=v.y; q[1]=fmaf(v.y,v.y,q[1]);
    s[2]+=v.z; q[2]=fmaf(v.z,v.z,q[2]);
    s[3]+=v.w; q[3]=fmaf(v.w,v.w,q[3]);
  }
  __shared__ float red[2048];
  #pragma unroll
  for (int i=0;i<4;i++){ red[tid*4+i] = s[i]; red[1024 + tid*4+i] = q[i]; }
  __syncthreads();
  if (tid < 32){
    float ts=0.f, tq=0.f;
    for (int m=0;m<32;m++){
      const int a = (m*8 + (tid>>2))*4 + (tid&3);
      ts += red[a]; tq += red[1024+a];
    }
    long long* dst = acc1 + (blockIdx.x & 7)*64;
    atomic_fx(&dst[tid], ts);
    atomic_fx(&dst[32+tid], tq);
  }
}

// ---------------- shared staging for K5/K6: 8 points x 32 rows of h1 into LDS ----------------
#define PSTRIDE 1160   // floats per point region (32 rows * 36) + 8 stagger
__device__ __forceinline__ void stage_h1(const float* __restrict__ x1, const float* __restrict__ bn1,
                                         float* __restrict__ h, int t0, int tid) {
  const int rlo = tid >> 3, cq = tid & 7;
  const float sc0 = bn1[cq*4+0], sc1 = bn1[cq*4+1], sc2 = bn1[cq*4+2], sc3 = bn1[cq*4+3];
  const float sh0 = bn1[32+cq*4+0], sh1 = bn1[32+cq*4+1], sh2 = bn1[32+cq*4+2], sh3 = bn1[32+cq*4+3];
  for (int k=0;k<8;k++){
    const int r = k*32 + rlo;
    const float4 v = *(const float4*)(x1 + (size_t)(t0 + r)*32 + cq*4);
    float* d = h + (r>>5)*PSTRIDE + (r&31)*36 + cq*4;
    d[0] = lrelu(fmaf(v.x, sc0, sh0));
    d[1] = lrelu(fmaf(v.y, sc1, sh1));
    d[2] = lrelu(fmaf(v.z, sc2, sh2));
    d[3] = lrelu(fmaf(v.w, sc3, sh3));
  }
}

// ---------------- K5: layer2 stats -> acc2[16][128] ----------------
__global__ __launch_bounds__(256) void k_stats2(const float* __restrict__ x1, const float* __restrict__ bn1,
    const float* __restrict__ w2, const float* __restrict__ b2, long long* __restrict__ acc2) {
  __shared__ float h[8*PSTRIDE];
  const int tid = threadIdx.x;
  const int t0 = blockIdx.x * 256;
  stage_h1(x1, bn1, h, t0, tid);
  __syncthreads();
  const int q = tid & 31, p = tid >> 5;
  const int o0 = 2*q, o1 = 2*q+1;
  float wa[32], wb[32];
  #pragma unroll
  for (int i=0;i<8;i++){
    const float4 A = *(const float4*)(w2 + o0*32 + i*4);
    wa[4*i+0]=A.x; wa[4*i+1]=A.y; wa[4*i+2]=A.z; wa[4*i+3]=A.w;
    const float4 B = *(const float4*)(w2 + o1*32 + i*4);
    wb[4*i+0]=B.x; wb[4*i+1]=B.y; wb[4*i+2]=B.z; wb[4*i+3]=B.w;
  }
  const float bb0 = b2[o0], bb1 = b2[o1];
  float s0=0.f, s1=0.f, q0=0.f, q1=0.f;
  const float* hp = h + p*PSTRIDE;
  for (int s=0;s<32;s++){
    const float* row = hp + s*36;
    float a0=bb0, a1=bb1;
    #pragma unroll
    for (int i=0;i<8;i++){
      const float4 hv = *(const float4*)(row + 4*i);
      a0 = fmaf(hv.x, wa[4*i+0], a0); a0 = fmaf(hv.y, wa[4*i+1], a0);
      a0 = fmaf(hv.z, wa[4*i+2], a0); a0 = fmaf(hv.w, wa[4*i+3], a0);
      a1 = fmaf(hv.x, wb[4*i+0], a1); a1 = fmaf(hv.y, wb[4*i+1], a1);
      a1 = fmaf(hv.z, wb[4*i+2], a1); a1 = fmaf(hv.w, wb[4*i+3], a1);
    }
    s0 += a0; q0 = fmaf(a0,a0,q0);
    s1 += a1; q1 = fmaf(a1,a1,q1);
  }
  __syncthreads();
  h[p*64+o0] = s0; h[p*64+o1] = s1;
  h[512 + p*64+o0] = q0; h[512 + p*64+o1] = q1;
  __syncthreads();
  if (tid < 128){
    const int o = tid & 63, half = tid >> 6;
    float acc = 0.f;
    #pragma unroll
    for (int pp=0;pp<8;pp++) acc += h[half*512 + pp*64 + o];
    atomic_fx(&acc2[(blockIdx.x & 15)*128 + half*64 + o], acc);
  }
}

// ---------------- K6: layer2 max (pre-bn2, monotone) + bn2 + lrelu + transposed write ----------------
__global__ __launch_bounds__(256) void k_final2(const float* __restrict__ x1, const float* __restrict__ bn1,
    const float* __restrict__ w2, const float* __restrict__ b2, const float* __restrict__ bn2,
    float* __restrict__ out) {
  __shared__ float h[8*PSTRIDE];
  const int tid = threadIdx.x;
  const int t0 = blockIdx.x * 256;
  stage_h1(x1, bn1, h, t0, tid);
  __syncthreads();
  const int q = tid & 31, p = tid >> 5;
  const int o0 = 2*q, o1 = 2*q+1;
  float wa[32], wb[32];
  #pragma unroll
  for (int i=0;i<8;i++){
    const float4 A = *(const float4*)(w2 + o0*32 + i*4);
    wa[4*i+0]=A.x; wa[4*i+1]=A.y; wa[4*i+2]=A.z; wa[4*i+3]=A.w;
    const float4 B = *(const float4*)(w2 + o1*32 + i*4);
    wb[4*i+0]=B.x; wb[4*i+1]=B.y; wb[4*i+2]=B.z; wb[4*i+3]=B.w;
  }
  const float bb0 = b2[o0], bb1 = b2[o1];
  float m0 = -3.0e38f, m1 = -3.0e38f;
  const float* hp = h + p*PSTRIDE;
  for (int s=0;s<32;s++){
    const float* row = hp + s*36;
    float a0=bb0, a1=bb1;
    #pragma unroll
    for (int i=0;i<8;i++){
      const float4 hv = *(const float4*)(row + 4*i);
      a0 = fmaf(hv.x, wa[4*i+0], a0); a0 = fmaf(hv.y, wa[4*i+1], a0);
      a0 = fmaf(hv.z, wa[4*i+2], a0); a0 = fmaf(hv.w, wa[4*i+3], a0);
      a1 = fmaf(hv.x, wb[4*i+0], a1); a1 = fmaf(hv.y, wb[4*i+1], a1);
      a1 = fmaf(hv.z, wb[4*i+2], a1); a1 = fmaf(hv.w, wb[4*i+3], a1);
    }
    m0 = fmaxf(m0, a0); m1 = fmaxf(m1, a1);
  }
  const float v0 = lrelu(fmaf(m0, bn2[o0], bn2[64+o0]));
  const float v1 = lrelu(fmaf(m1, bn2[o1], bn2[64+o1]));
  __syncthreads();
  h[p*65 + o0] = v0; h[p*65 + o1] = v1;   // res[8][65]
  __syncthreads();
  if (tid < 128){
    const int o = tid >> 1, pr = tid & 1;
    float4 v;
    v.x = h[(pr*4+0)*65 + o];
    v.y = h[(pr*4+1)*65 + o];
    v.z = h[(pr*4+2)*65 + o];
    v.w = h[(pr*4+3)*65 + o];
    const int np = blockIdx.x * 8;
    const int b = np >> 12, n0 = np & (NN-1);
    *(float4*)(out + (size_t)(b*64 + o)*NN + n0 + pr*4) = v;
  }
}

extern "C" void kernel_launch(void* const* d_in, const int* in_sizes, int n_in,
                              void* d_out, int out_size, void* d_ws, size_t ws_size,
                              hipStream_t stream) {
  const float* pts = (const float*)d_in[0];
  const float* w0  = (const float*)d_in[1];
  const float* b0  = (const float*)d_in[2];
  const float* g0  = (const float*)d_in[3];
  const float* be0 = (const float*)d_in[4];
  const float* w1  = (const float*)d_in[5];
  const float* b1  = (const float*)d_in[6];
  const float* g1  = (const float*)d_in[7];
  const float* be1 = (const float*)d_in[8];
  const float* w2  = (const float*)d_in[9];
  const float* b2  = (const float*)d_in[10];
  const float* g2  = (const float*)d_in[11];
  const float* be2 = (const float*)d_in[12];
  float* out = (float*)d_out;

  char* ws = (char*)d_ws;
  int*       idx  = (int*)      (ws + 0);          // 2 MB
  float*     x1   = (float*)    (ws + 2097152);    // 67.1 MB -> 69206016
  long long* acc0 = (long long*)(ws + 69206016);   // 8*27*8  = 1728 B (pad to 2048)
  long long* acc1 = (long long*)(ws + 69208064);   // 8*64*8  = 4096 B
  long long* acc2 = (long long*)(ws + 69212160);   // 16*128*8= 16384 B
  float*     bn0  = (float*)    (ws + 69228544);   // 64 floats
  float*     bn1  = (float*)    (ws + 69228800);   // 64 floats
  float*     bn2  = (float*)    (ws + 69229056);   // 128 floats

  // zero the i64 accumulators (22528 B starting at acc0)
  hipMemsetAsync((void*)acc0, 0, 22528, stream);

  k_ballquery<<<512,  256, 0, stream>>>(pts, idx);
  k_stats0g <<<512,  256, 0, stream>>>(pts, idx, acc0);
  k_fin0g   <<<1,    256, 0, stream>>>(acc0, w0, b0, g0, be0, bn0);
  k_layer01 <<<1024, 256, 0, stream>>>(pts, idx, w0, b0, bn0, w1, b1, x1);
  k_stats1  <<<1024, 256, 0, stream>>>(x1, acc1);
  k_fin     <<<1,    256, 0, stream>>>(acc1, 8, 32, g1, be1, bn1);
  k_stats2  <<<2048, 256, 0, stream>>>(x1, bn1, w2, b2, acc2);
  k_fin     <<<1,    256, 0, stream>>>(acc2, 16, 64, g2, be2, bn2);
  k_final2  <<<2048, 256, 0, stream>>>(x1, bn1, w2, b2, bn2, out);
}

// Round 6
// 158.549 us; speedup vs baseline: 12.4199x; 1.3686x over previous
//
#include <hip/hip_runtime.h>
#include <math.h>

#define NB 4
#define NN 4096
#define NS 32
#define NTOT (NB*NN*NS)   // 524288
#define FXSCALE 16777216.0   // 2^24 fixed-point scale for deterministic i64 atomics

__device__ __forceinline__ float lrelu(float x){ return x > 0.0f ? x : 0.2f*x; }
__device__ __forceinline__ int symoff(int i, int j){
  return (i<=j) ? (i*(11-i))/2 + j : (j*(11-j))/2 + i;   // 6x6 sym packed index
}
__device__ __forceinline__ void atomic_fx(long long* p, float v){
  long long q = llrint((double)v * FXSCALE);            // double: exact for |v|<2^29
  atomicAdd((unsigned long long*)p, (unsigned long long)q);
}
__device__ __forceinline__ float fx2f(long long q){ return (float)((double)q * (1.0/FXSCALE)); }

// ---------------- K1: ball query (first NS indices within radius, ascending) ----------------
__global__ __launch_bounds__(256) void k_ballquery(const float* __restrict__ pts, int* __restrict__ idx) {
  __shared__ float sx[NN], sy[NN], sz[NN], sq[NN];
  const int b = blockIdx.x >> 7;
  const int tile = blockIdx.x & 127;
  const float* p = pts + b*3*NN;
  for (int i = threadIdx.x; i < NN; i += 256) {
    float x = p[i], y = p[NN+i], z = p[2*NN+i];
    sx[i]=x; sy[i]=y; sz[i]=z;
    sq[i] = __fadd_rn(__fadd_rn(__fmul_rn(x,x), __fmul_rn(y,y)), __fmul_rn(z,z));
  }
  __syncthreads();
  const int wave = threadIdx.x >> 6;
  const int lane = threadIdx.x & 63;
  for (int w = 0; w < 8; ++w) {
    const int n = tile*32 + wave*8 + w;
    const float cx = sx[n], cy = sy[n], cz = sz[n], cq = sq[n];
    int* row = idx + (((b << 12) + n) << 5);
    int count = 0;
    int first = 0;
    for (int jb = 0; jb < NN; jb += 64) {
      const int j = jb + lane;
      float dot = fmaf(sz[j], cz, fmaf(sy[j], cy, __fmul_rn(sx[j], cx)));
      float r = __fsub_rn(__fadd_rn(cq, sq[j]), __fmul_rn(2.0f, dot));
      bool valid = !(r > 0.04f);
      unsigned long long m = __ballot(valid);
      if (count == 0 && m != 0ull) first = jb + (int)__builtin_ctzll(m);
      int pos = count + (int)__popcll(m & ((1ull << lane) - 1ull));
      if (valid && pos < NS) row[pos] = j;
      count += (int)__popcll(m);
      if (count >= NS) break;
    }
    for (int pp = count + lane; pp < NS; pp += 64) row[pp] = first;
  }
}

// ---------------- K2: edge-feature Gram stats -> acc0[8][27] (i64 atomics) ----------------
__global__ __launch_bounds__(256) void k_stats0g(const float* __restrict__ pts, const int* __restrict__ idx,
                                                 long long* __restrict__ acc0) {
  float S[6], M[21];
  #pragma unroll
  for (int i=0;i<6;i++) S[i]=0.f;
  #pragma unroll
  for (int i=0;i<21;i++) M[i]=0.f;
  const int base = blockIdx.x * 1024;
  for (int k=0;k<4;k++){
    const int t = base + k*256 + (int)threadIdx.x;
    const int b = t >> 17;
    const int n = (t >> 5) & (NN-1);
    const int j = idx[t];
    const float* p = pts + b*3*NN;
    float v[6];
    v[0]=p[n]; v[1]=p[NN+n]; v[2]=p[2*NN+n];
    v[3]=p[j]-v[0]; v[4]=p[NN+j]-v[1]; v[5]=p[2*NN+j]-v[2];
    #pragma unroll
    for (int i=0;i<6;i++) S[i] += v[i];
    int c=0;
    #pragma unroll
    for (int i=0;i<6;i++)
      #pragma unroll
      for (int jj=i;jj<6;jj++){ M[c] = fmaf(v[i], v[jj], M[c]); c++; }
  }
  #pragma unroll
  for (int off=32; off>=1; off>>=1){
    #pragma unroll
    for (int i=0;i<6;i++)  S[i] += __shfl_xor(S[i], off);
    #pragma unroll
    for (int i=0;i<21;i++) M[i] += __shfl_xor(M[i], off);
  }
  __shared__ float red[4][27];
  const int wave = threadIdx.x >> 6, lane = threadIdx.x & 63;
  if (lane == 0){
    #pragma unroll
    for (int i=0;i<6;i++)  red[wave][i]   = S[i];
    #pragma unroll
    for (int i=0;i<21;i++) red[wave][6+i] = M[i];
  }
  __syncthreads();
  if (threadIdx.x < 27){
    float a = red[0][threadIdx.x]+red[1][threadIdx.x]+red[2][threadIdx.x]+red[3][threadIdx.x];
    atomic_fx(&acc0[(blockIdx.x & 7)*27 + threadIdx.x], a);
  }
}

// ---------------- finalize bn0 from Gram accumulators ----------------
__global__ __launch_bounds__(256) void k_fin0g(const long long* __restrict__ acc0,
    const float* __restrict__ w0, const float* __restrict__ b0,
    const float* __restrict__ g0, const float* __restrict__ be0, float* __restrict__ bn0) {
  __shared__ float SM[27];
  if (threadIdx.x < 27){
    long long s = 0;
    #pragma unroll
    for (int k=0;k<8;k++) s += acc0[k*27 + threadIdx.x];
    SM[threadIdx.x] = fx2f(s);
  }
  __syncthreads();
  if (threadIdx.x < 32){
    const int cch = threadIdx.x;
    float w[6];
    #pragma unroll
    for (int i=0;i<6;i++) w[i] = w0[cch*6+i];
    float dot=0.f;
    #pragma unroll
    for (int i=0;i<6;i++) dot = fmaf(w[i], SM[i], dot);
    float qd=0.f;
    #pragma unroll
    for (int i=0;i<6;i++){
      float ti=0.f;
      #pragma unroll
      for (int j=0;j<6;j++) ti = fmaf(w[j], SM[6+symoff(i,j)], ti);
      qd = fmaf(w[i], ti, qd);
    }
    const float NT = (float)NTOT;
    const float bb = b0[cch];
    float s1 = dot + NT*bb;
    float s2 = qd + 2.f*bb*dot + NT*bb*bb;
    const float inv = 1.0f / NT;
    float mean = s1 * inv;
    float var  = fmaxf(s2*inv - mean*mean, 0.0f);
    float sc = g0[cch] / sqrtf(var + 1e-5f);
    bn0[cch] = sc;
    bn0[32+cch] = be0[cch] - mean*sc;
  }
}

// ---------------- generic finalize: acc[NCOPY][2C] i64 -> scale/shift ----------------
__global__ __launch_bounds__(256) void k_fin(const long long* __restrict__ acc, int ncopy, int C,
    const float* __restrict__ g, const float* __restrict__ beta, float* __restrict__ bn) {
  if ((int)threadIdx.x < C) {
    const int c = threadIdx.x;
    long long ts = 0, tq = 0;
    for (int k=0;k<ncopy;k++){ ts += acc[k*2*C + c]; tq += acc[k*2*C + C + c]; }
    const float inv = 1.0f / (float)NTOT;
    float m = fx2f(ts) * inv;
    float var = fmaxf(fx2f(tq)*inv - m*m, 0.0f);
    float sc = g[c] / sqrtf(var + 1e-5f);
    bn[c] = sc;
    bn[C+c] = beta[c] - m*sc;
  }
}

// ---------------- K3: layer0+bn0+lrelu+layer1 -> x1, with fused layer1 stats ----------------
// 1 row/thread, 2048 blocks. LDS stride-257 layout: bank = (ch + r) % 32 -> conflict-free
// column sums without per-thread ls[32]/lq[32] register blowup.
#define LST 257
__global__ __launch_bounds__(256) void k_layer01s(const float* __restrict__ pts, const int* __restrict__ idx,
    const float* __restrict__ w0, const float* __restrict__ b0, const float* __restrict__ bn0,
    const float* __restrict__ w1, const float* __restrict__ b1,
    float* __restrict__ x1, long long* __restrict__ acc1) {
  __shared__ float st[32*LST];   // [ch][row_local], stride 257
  const int tid = threadIdx.x;
  const int t = blockIdx.x * 256 + tid;
  const int b = t >> 17;
  const int n = (t >> 5) & (NN-1);
  const int j = idx[t];
  const float* p = pts + b*3*NN;
  const float cx = p[n], cy = p[NN+n], cz = p[2*NN+n];
  const float e3 = p[j]-cx, e4 = p[NN+j]-cy, e5 = p[2*NN+j]-cz;
  float h0[32];
  #pragma unroll
  for (int c=0;c<32;c++){
    float v = b0[c];
    v = fmaf(cx, w0[c*6+0], v);
    v = fmaf(cy, w0[c*6+1], v);
    v = fmaf(cz, w0[c*6+2], v);
    v = fmaf(e3, w0[c*6+3], v);
    v = fmaf(e4, w0[c*6+4], v);
    v = fmaf(e5, w0[c*6+5], v);
    h0[c] = lrelu(fmaf(v, bn0[c], bn0[32+c]));
  }
  float4* dst4 = (float4*)(x1 + (size_t)t*32);
  #pragma unroll
  for (int og=0; og<8; ++og){
    float a0=b1[4*og+0], a1=b1[4*og+1], a2=b1[4*og+2], a3=b1[4*og+3];
    #pragma unroll
    for (int c=0;c<32;c++){
      a0 = fmaf(h0[c], w1[(4*og+0)*32+c], a0);
      a1 = fmaf(h0[c], w1[(4*og+1)*32+c], a1);
      a2 = fmaf(h0[c], w1[(4*og+2)*32+c], a2);
      a3 = fmaf(h0[c], w1[(4*og+3)*32+c], a3);
    }
    dst4[og] = make_float4(a0,a1,a2,a3);
    st[(4*og+0)*LST + tid] = a0;
    st[(4*og+1)*LST + tid] = a1;
    st[(4*og+2)*LST + tid] = a2;
    st[(4*og+3)*LST + tid] = a3;
  }
  __syncthreads();
  // column partials: thread (ch = tid&31, grp = tid>>5) sums 32 rows
  const int ch = tid & 31, grp = tid >> 5;
  float s = 0.f, q = 0.f;
  #pragma unroll
  for (int r=0;r<32;r++){
    float v = st[ch*LST + grp*32 + r];
    s += v; q = fmaf(v,v,q);
  }
  __syncthreads();
  st[grp*64 + ch] = s;
  st[grp*64 + 32 + ch] = q;
  __syncthreads();
  if (tid < 64){
    const int c = tid & 31, half = tid >> 5;
    float acc = 0.f;
    #pragma unroll
    for (int g2=0; g2<8; ++g2) acc += st[g2*64 + half*32 + c];
    atomic_fx(&acc1[(blockIdx.x & 7)*64 + half*32 + c], acc);
  }
}

// ---------------- shared staging for K5: 8 points x 32 rows of h1 into LDS ----------------
#define PSTRIDE 1160   // floats per point region (32 rows * 36) + 8 stagger
__device__ __forceinline__ void stage_h1(const float* __restrict__ x1, const float* __restrict__ bn1,
                                         float* __restrict__ h, int t0, int tid) {
  const int rlo = tid >> 3, cq = tid & 7;
  const float sc0 = bn1[cq*4+0], sc1 = bn1[cq*4+1], sc2 = bn1[cq*4+2], sc3 = bn1[cq*4+3];
  const float sh0 = bn1[32+cq*4+0], sh1 = bn1[32+cq*4+1], sh2 = bn1[32+cq*4+2], sh3 = bn1[32+cq*4+3];
  for (int k=0;k<8;k++){
    const int r = k*32 + rlo;
    const float4 v = *(const float4*)(x1 + (size_t)(t0 + r)*32 + cq*4);
    float* d = h + (r>>5)*PSTRIDE + (r&31)*36 + cq*4;
    d[0] = lrelu(fmaf(v.x, sc0, sh0));
    d[1] = lrelu(fmaf(v.y, sc1, sh1));
    d[2] = lrelu(fmaf(v.z, sc2, sh2));
    d[3] = lrelu(fmaf(v.w, sc3, sh3));
  }
}

// ---------------- K5: fused layer2 stats + pre-bn2 max. pmax written into own dead x1 slice ----------------
__global__ __launch_bounds__(256) void k_l2fused(float* __restrict__ x1, const float* __restrict__ bn1,
    const float* __restrict__ w2, const float* __restrict__ b2, long long* __restrict__ acc2) {
  __shared__ float h[8*PSTRIDE];
  const int tid = threadIdx.x;
  const int t0 = blockIdx.x * 256;
  stage_h1(x1, bn1, h, t0, tid);      // reads ALL of this block's x1 slice before the barrier
  __syncthreads();
  const int q = tid & 31, p = tid >> 5;
  const int o0 = 2*q, o1 = 2*q+1;
  float wa[32], wb[32];
  #pragma unroll
  for (int i=0;i<8;i++){
    const float4 A = *(const float4*)(w2 + o0*32 + i*4);
    wa[4*i+0]=A.x; wa[4*i+1]=A.y; wa[4*i+2]=A.z; wa[4*i+3]=A.w;
    const float4 B = *(const float4*)(w2 + o1*32 + i*4);
    wb[4*i+0]=B.x; wb[4*i+1]=B.y; wb[4*i+2]=B.z; wb[4*i+3]=B.w;
  }
  const float bb0 = b2[o0], bb1 = b2[o1];
  float s0=0.f, s1=0.f, q0=0.f, q1=0.f;
  float m0 = -3.0e38f, m1 = -3.0e38f;
  const float* hp = h + p*PSTRIDE;
  for (int s=0;s<32;s++){
    const float* row = hp + s*36;
    float a0=bb0, a1=bb1;
    #pragma unroll
    for (int i=0;i<8;i++){
      const float4 hv = *(const float4*)(row + 4*i);
      a0 = fmaf(hv.x, wa[4*i+0], a0); a0 = fmaf(hv.y, wa[4*i+1], a0);
      a0 = fmaf(hv.z, wa[4*i+2], a0); a0 = fmaf(hv.w, wa[4*i+3], a0);
      a1 = fmaf(hv.x, wb[4*i+0], a1); a1 = fmaf(hv.y, wb[4*i+1], a1);
      a1 = fmaf(hv.z, wb[4*i+2], a1); a1 = fmaf(hv.w, wb[4*i+3], a1);
    }
    s0 += a0; q0 = fmaf(a0,a0,q0); m0 = fmaxf(m0, a0);
    s1 += a1; q1 = fmaf(a1,a1,q1); m1 = fmaxf(m1, a1);
  }
  // pre-bn2 max into this block's own (now dead) x1 region: pm[pt] at x1 + pt*1024 floats
  float* pm = x1 + (size_t)(t0 + p*32)*32;
  pm[o0] = m0; pm[o1] = m1;
  // block-reduce sums -> atomics
  __syncthreads();
  h[p*64+o0] = s0; h[p*64+o1] = s1;
  h[512 + p*64+o0] = q0; h[512 + p*64+o1] = q1;
  __syncthreads();
  if (tid < 128){
    const int o = tid & 63, half = tid >> 6;
    float acc = 0.f;
    #pragma unroll
    for (int pp=0;pp<8;pp++) acc += h[half*512 + pp*64 + o];
    atomic_fx(&acc2[(blockIdx.x & 15)*128 + half*64 + o], acc);
  }
}

// ---------------- K6: bn2 + lrelu on per-point maxes, transposed write to out (B,64,N) ----------------
__global__ __launch_bounds__(256) void k_out(const float* __restrict__ x1, const float* __restrict__ bn2,
                                             float* __restrict__ out) {
  __shared__ float sm[64*65];   // [ch][pt]
  const int tid = threadIdx.x;
  const int p0 = blockIdx.x * 64;              // 64 points per block, all within one batch
  // load: 4 threads per point, each 4 float4 of the 64-float pmax row (stride 1024 floats/pt)
  const int ptl = tid >> 2, quad = tid & 3;
  const float* src = x1 + (size_t)(p0 + ptl)*1024 + quad*16;
  #pragma unroll
  for (int k=0;k<4;k++){
    const float4 v = *(const float4*)(src + k*4);
    const int ch = quad*16 + k*4;
    sm[(ch+0)*65 + ptl] = v.x;
    sm[(ch+1)*65 + ptl] = v.y;
    sm[(ch+2)*65 + ptl] = v.z;
    sm[(ch+3)*65 + ptl] = v.w;
  }
  __syncthreads();
  const int b = p0 >> 12, n0 = p0 & (NN-1);
  #pragma unroll
  for (int i=0;i<4;i++){
    const int j = tid + i*256;
    const int ch = j >> 4, f4 = j & 15;
    const float sc = bn2[ch], sh = bn2[64+ch];
    float4 v;
    v.x = lrelu(fmaf(sm[ch*65 + f4*4+0], sc, sh));
    v.y = lrelu(fmaf(sm[ch*65 + f4*4+1], sc, sh));
    v.z = lrelu(fmaf(sm[ch*65 + f4*4+2], sc, sh));
    v.w = lrelu(fmaf(sm[ch*65 + f4*4+3], sc, sh));
    *(float4*)(out + (size_t)(b*64 + ch)*NN + n0 + f4*4) = v;
  }
}

extern "C" void kernel_launch(void* const* d_in, const int* in_sizes, int n_in,
                              void* d_out, int out_size, void* d_ws, size_t ws_size,
                              hipStream_t stream) {
  const float* pts = (const float*)d_in[0];
  const float* w0  = (const float*)d_in[1];
  const float* b0  = (const float*)d_in[2];
  const float* g0  = (const float*)d_in[3];
  const float* be0 = (const float*)d_in[4];
  const float* w1  = (const float*)d_in[5];
  const float* b1  = (const float*)d_in[6];
  const float* g1  = (const float*)d_in[7];
  const float* be1 = (const float*)d_in[8];
  const float* w2  = (const float*)d_in[9];
  const float* b2  = (const float*)d_in[10];
  const float* g2  = (const float*)d_in[11];
  const float* be2 = (const float*)d_in[12];
  float* out = (float*)d_out;

  char* ws = (char*)d_ws;
  int*       idx  = (int*)      (ws + 0);          // 2 MB
  float*     x1   = (float*)    (ws + 2097152);    // 67.1 MB -> 69206016 (pmax overlaid in-place)
  long long* acc0 = (long long*)(ws + 69206016);   // 8*27*8  (pad to 2048)
  long long* acc1 = (long long*)(ws + 69208064);   // 8*64*8  = 4096 B
  long long* acc2 = (long long*)(ws + 69212160);   // 16*128*8= 16384 B
  float*     bn0  = (float*)    (ws + 69228544);
  float*     bn1  = (float*)    (ws + 69228800);
  float*     bn2  = (float*)    (ws + 69229056);

  hipMemsetAsync((void*)acc0, 0, 22528, stream);

  k_ballquery<<<512,  256, 0, stream>>>(pts, idx);
  k_stats0g <<<512,  256, 0, stream>>>(pts, idx, acc0);
  k_fin0g   <<<1,    256, 0, stream>>>(acc0, w0, b0, g0, be0, bn0);
  k_layer01s<<<2048, 256, 0, stream>>>(pts, idx, w0, b0, bn0, w1, b1, x1, acc1);
  k_fin     <<<1,    256, 0, stream>>>(acc1, 8, 32, g1, be1, bn1);
  k_l2fused <<<2048, 256, 0, stream>>>(x1, bn1, w2, b2, acc2);
  k_fin     <<<1,    256, 0, stream>>>(acc2, 16, 64, g2, be2, bn2);
  k_out     <<<256,  256, 0, stream>>>(x1, bn2, out);
}

// Round 7
// 141.279 us; speedup vs baseline: 13.9381x; 1.1222x over previous
//
#include <hip/hip_runtime.h>
#include <math.h>

#define NB 4
#define NN 4096
#define NS 32
#define NTOT (NB*NN*NS)   // 524288
#define FXSCALE 16777216.0   // 2^24 fixed-point scale for deterministic i64 atomics

__device__ __forceinline__ float lrelu(float x){ return x > 0.0f ? x : 0.2f*x; }
__device__ __forceinline__ int symoff(int i, int j){
  return (i<=j) ? (i*(11-i))/2 + j : (j*(11-j))/2 + i;   // 6x6 sym packed index
}
__device__ __forceinline__ void atomic_fx(long long* p, float v){
  long long q = llrint((double)v * FXSCALE);            // double: exact for |v|<2^29
  atomicAdd((unsigned long long*)p, (unsigned long long)q);
}
__device__ __forceinline__ float fx2f(long long q){ return (float)((double)q * (1.0/FXSCALE)); }

// ---------------- K1: ball query (first NS indices within radius, ascending) ----------------
__global__ __launch_bounds__(256) void k_ballquery(const float* __restrict__ pts, int* __restrict__ idx) {
  __shared__ float sx[NN], sy[NN], sz[NN], sq[NN];
  const int b = blockIdx.x >> 7;
  const int tile = blockIdx.x & 127;
  const float* p = pts + b*3*NN;
  for (int i = threadIdx.x; i < NN; i += 256) {
    float x = p[i], y = p[NN+i], z = p[2*NN+i];
    sx[i]=x; sy[i]=y; sz[i]=z;
    sq[i] = __fadd_rn(__fadd_rn(__fmul_rn(x,x), __fmul_rn(y,y)), __fmul_rn(z,z));
  }
  __syncthreads();
  const int wave = threadIdx.x >> 6;
  const int lane = threadIdx.x & 63;
  for (int w = 0; w < 8; ++w) {
    const int n = tile*32 + wave*8 + w;
    const float cx = sx[n], cy = sy[n], cz = sz[n], cq = sq[n];
    int* row = idx + (((b << 12) + n) << 5);
    int count = 0;
    int first = 0;
    for (int jb = 0; jb < NN; jb += 64) {
      const int j = jb + lane;
      float dot = fmaf(sz[j], cz, fmaf(sy[j], cy, __fmul_rn(sx[j], cx)));
      float r = __fsub_rn(__fadd_rn(cq, sq[j]), __fmul_rn(2.0f, dot));
      bool valid = !(r > 0.04f);
      unsigned long long m = __ballot(valid);
      if (count == 0 && m != 0ull) first = jb + (int)__builtin_ctzll(m);
      int pos = count + (int)__popcll(m & ((1ull << lane) - 1ull));
      if (valid && pos < NS) row[pos] = j;
      count += (int)__popcll(m);
      if (count >= NS) break;
    }
    for (int pp = count + lane; pp < NS; pp += 64) row[pp] = first;
  }
}

// ---------------- K2: edge-feature Gram stats -> acc0[8][27] (i64 atomics) ----------------
__global__ __launch_bounds__(256) void k_stats0g(const float* __restrict__ pts, const int* __restrict__ idx,
                                                 long long* __restrict__ acc0) {
  float S[6], M[21];
  #pragma unroll
  for (int i=0;i<6;i++) S[i]=0.f;
  #pragma unroll
  for (int i=0;i<21;i++) M[i]=0.f;
  const int base = blockIdx.x * 1024;
  for (int k=0;k<4;k++){
    const int t = base + k*256 + (int)threadIdx.x;
    const int b = t >> 17;
    const int n = (t >> 5) & (NN-1);
    const int j = idx[t];
    const float* p = pts + b*3*NN;
    float v[6];
    v[0]=p[n]; v[1]=p[NN+n]; v[2]=p[2*NN+n];
    v[3]=p[j]-v[0]; v[4]=p[NN+j]-v[1]; v[5]=p[2*NN+j]-v[2];
    #pragma unroll
    for (int i=0;i<6;i++) S[i] += v[i];
    int c=0;
    #pragma unroll
    for (int i=0;i<6;i++)
      #pragma unroll
      for (int jj=i;jj<6;jj++){ M[c] = fmaf(v[i], v[jj], M[c]); c++; }
  }
  #pragma unroll
  for (int off=32; off>=1; off>>=1){
    #pragma unroll
    for (int i=0;i<6;i++)  S[i] += __shfl_xor(S[i], off);
    #pragma unroll
    for (int i=0;i<21;i++) M[i] += __shfl_xor(M[i], off);
  }
  __shared__ float red[4][27];
  const int wave = threadIdx.x >> 6, lane = threadIdx.x & 63;
  if (lane == 0){
    #pragma unroll
    for (int i=0;i<6;i++)  red[wave][i]   = S[i];
    #pragma unroll
    for (int i=0;i<21;i++) red[wave][6+i] = M[i];
  }
  __syncthreads();
  if (threadIdx.x < 27){
    float a = red[0][threadIdx.x]+red[1][threadIdx.x]+red[2][threadIdx.x]+red[3][threadIdx.x];
    atomic_fx(&acc0[(blockIdx.x & 7)*27 + threadIdx.x], a);
  }
}

// ---------------- finalize bn0 from Gram accumulators ----------------
__global__ __launch_bounds__(256) void k_fin0g(const long long* __restrict__ acc0,
    const float* __restrict__ w0, const float* __restrict__ b0,
    const float* __restrict__ g0, const float* __restrict__ be0, float* __restrict__ bn0) {
  __shared__ float SM[27];
  if (threadIdx.x < 27){
    long long s = 0;
    #pragma unroll
    for (int k=0;k<8;k++) s += acc0[k*27 + threadIdx.x];
    SM[threadIdx.x] = fx2f(s);
  }
  __syncthreads();
  if (threadIdx.x < 32){
    const int cch = threadIdx.x;
    float w[6];
    #pragma unroll
    for (int i=0;i<6;i++) w[i] = w0[cch*6+i];
    float dot=0.f;
    #pragma unroll
    for (int i=0;i<6;i++) dot = fmaf(w[i], SM[i], dot);
    float qd=0.f;
    #pragma unroll
    for (int i=0;i<6;i++){
      float ti=0.f;
      #pragma unroll
      for (int j=0;j<6;j++) ti = fmaf(w[j], SM[6+symoff(i,j)], ti);
      qd = fmaf(w[i], ti, qd);
    }
    const float NT = (float)NTOT;
    const float bb = b0[cch];
    float s1 = dot + NT*bb;
    float s2 = qd + 2.f*bb*dot + NT*bb*bb;
    const float inv = 1.0f / NT;
    float mean = s1 * inv;
    float var  = fmaxf(s2*inv - mean*mean, 0.0f);
    float sc = g0[cch] / sqrtf(var + 1e-5f);
    bn0[cch] = sc;
    bn0[32+cch] = be0[cch] - mean*sc;
  }
}

// ---------------- generic finalize: acc[NCOPY][2C] i64 -> scale/shift ----------------
__global__ __launch_bounds__(256) void k_fin(const long long* __restrict__ acc, int ncopy, int C,
    const float* __restrict__ g, const float* __restrict__ beta, float* __restrict__ bn) {
  if ((int)threadIdx.x < C) {
    const int c = threadIdx.x;
    long long ts = 0, tq = 0;
    for (int k=0;k<ncopy;k++){ ts += acc[k*2*C + c]; tq += acc[k*2*C + C + c]; }
    const float inv = 1.0f / (float)NTOT;
    float m = fx2f(ts) * inv;
    float var = fmaxf(fx2f(tq)*inv - m*m, 0.0f);
    float sc = g[c] / sqrtf(var + 1e-5f);
    bn[c] = sc;
    bn[C+c] = beta[c] - m*sc;
  }
}

// ---------------- K3: layer0+bn0+lrelu+layer1 -> x1 (coalesced via LDS), fused layer1 stats ----------------
// 1 row/thread, 2048 blocks. st[ch][row] stride-257 (bank = ch+row mod 32).
// x1 stores go through LDS transpose: per instruction a wave writes 1 KB contiguous.
#define LST 257
__global__ __launch_bounds__(256) void k_layer01s(const float* __restrict__ pts, const int* __restrict__ idx,
    const float* __restrict__ w0, const float* __restrict__ b0, const float* __restrict__ bn0,
    const float* __restrict__ w1, const float* __restrict__ b1,
    float* __restrict__ x1, long long* __restrict__ acc1) {
  __shared__ float st[32*LST];   // [ch][row_local], stride 257
  const int tid = threadIdx.x;
  const int t0 = blockIdx.x * 256;
  const int t = t0 + tid;
  const int b = t >> 17;
  const int n = (t >> 5) & (NN-1);
  const int j = idx[t];
  const float* p = pts + b*3*NN;
  const float cx = p[n], cy = p[NN+n], cz = p[2*NN+n];
  const float e3 = p[j]-cx, e4 = p[NN+j]-cy, e5 = p[2*NN+j]-cz;
  float h0[32];
  #pragma unroll
  for (int c=0;c<32;c++){
    float v = b0[c];
    v = fmaf(cx, w0[c*6+0], v);
    v = fmaf(cy, w0[c*6+1], v);
    v = fmaf(cz, w0[c*6+2], v);
    v = fmaf(e3, w0[c*6+3], v);
    v = fmaf(e4, w0[c*6+4], v);
    v = fmaf(e5, w0[c*6+5], v);
    h0[c] = lrelu(fmaf(v, bn0[c], bn0[32+c]));
  }
  #pragma unroll
  for (int og=0; og<8; ++og){
    float a0=b1[4*og+0], a1=b1[4*og+1], a2=b1[4*og+2], a3=b1[4*og+3];
    #pragma unroll
    for (int c=0;c<32;c++){
      a0 = fmaf(h0[c], w1[(4*og+0)*32+c], a0);
      a1 = fmaf(h0[c], w1[(4*og+1)*32+c], a1);
      a2 = fmaf(h0[c], w1[(4*og+2)*32+c], a2);
      a3 = fmaf(h0[c], w1[(4*og+3)*32+c], a3);
    }
    st[(4*og+0)*LST + tid] = a0;
    st[(4*og+1)*LST + tid] = a1;
    st[(4*og+2)*LST + tid] = a2;
    st[(4*og+3)*LST + tid] = a3;
  }
  __syncthreads();
  // coalesced x1 write: thread (row = k*32 + tid>>3, chq = tid&7) writes one float4.
  // Wave instruction footprint: 8 rows x 128 B = 1 KB contiguous.
  {
    const int rlo = tid >> 3, chq = tid & 7;
    #pragma unroll
    for (int k=0;k<8;k++){
      const int row = k*32 + rlo;
      float4 v;
      v.x = st[(chq*4+0)*LST + row];
      v.y = st[(chq*4+1)*LST + row];
      v.z = st[(chq*4+2)*LST + row];
      v.w = st[(chq*4+3)*LST + row];
      *(float4*)(x1 + (size_t)(t0 + row)*32 + chq*4) = v;
    }
  }
  // column partials: thread (ch = tid&31, grp = tid>>5) sums 32 rows (reads only)
  const int ch = tid & 31, grp = tid >> 5;
  float s = 0.f, q = 0.f;
  #pragma unroll
  for (int r=0;r<32;r++){
    float v = st[ch*LST + grp*32 + r];
    s += v; q = fmaf(v,v,q);
  }
  __syncthreads();
  st[grp*64 + ch] = s;            // clobbers ch0/ch1 rows - x1 write already done
  st[grp*64 + 32 + ch] = q;
  __syncthreads();
  if (tid < 64){
    const int c = tid & 31, half = tid >> 5;
    float acc = 0.f;
    #pragma unroll
    for (int g2=0; g2<8; ++g2) acc += st[g2*64 + half*32 + c];
    atomic_fx(&acc1[(blockIdx.x & 7)*64 + half*32 + c], acc);
  }
}

// ---------------- shared staging for K5: 8 points x 32 rows of h1 into LDS ----------------
#define PSTRIDE 1160   // floats per point region (32 rows * 36) + 8 stagger
__device__ __forceinline__ void stage_h1(const float* __restrict__ x1, const float* __restrict__ bn1,
                                         float* __restrict__ h, int t0, int tid) {
  const int rlo = tid >> 3, cq = tid & 7;
  const float sc0 = bn1[cq*4+0], sc1 = bn1[cq*4+1], sc2 = bn1[cq*4+2], sc3 = bn1[cq*4+3];
  const float sh0 = bn1[32+cq*4+0], sh1 = bn1[32+cq*4+1], sh2 = bn1[32+cq*4+2], sh3 = bn1[32+cq*4+3];
  for (int k=0;k<8;k++){
    const int r = k*32 + rlo;
    const float4 v = *(const float4*)(x1 + (size_t)(t0 + r)*32 + cq*4);
    float* d = h + (r>>5)*PSTRIDE + (r&31)*36 + cq*4;
    d[0] = lrelu(fmaf(v.x, sc0, sh0));
    d[1] = lrelu(fmaf(v.y, sc1, sh1));
    d[2] = lrelu(fmaf(v.z, sc2, sh2));
    d[3] = lrelu(fmaf(v.w, sc3, sh3));
  }
}

// ---------------- K5: fused layer2 stats + pre-bn2 max. pmax written into own dead x1 slice ----------------
__global__ __launch_bounds__(256) void k_l2fused(float* __restrict__ x1, const float* __restrict__ bn1,
    const float* __restrict__ w2, const float* __restrict__ b2, long long* __restrict__ acc2) {
  __shared__ float h[8*PSTRIDE];
  const int tid = threadIdx.x;
  const int t0 = blockIdx.x * 256;
  stage_h1(x1, bn1, h, t0, tid);      // reads ALL of this block's x1 slice before the barrier
  __syncthreads();
  const int q = tid & 31, p = tid >> 5;
  const int o0 = 2*q, o1 = 2*q+1;
  float wa[32], wb[32];
  #pragma unroll
  for (int i=0;i<8;i++){
    const float4 A = *(const float4*)(w2 + o0*32 + i*4);
    wa[4*i+0]=A.x; wa[4*i+1]=A.y; wa[4*i+2]=A.z; wa[4*i+3]=A.w;
    const float4 B = *(const float4*)(w2 + o1*32 + i*4);
    wb[4*i+0]=B.x; wb[4*i+1]=B.y; wb[4*i+2]=B.z; wb[4*i+3]=B.w;
  }
  const float bb0 = b2[o0], bb1 = b2[o1];
  float s0=0.f, s1=0.f, q0=0.f, q1=0.f;
  float m0 = -3.0e38f, m1 = -3.0e38f;
  const float* hp = h + p*PSTRIDE;
  for (int s=0;s<32;s++){
    const float* row = hp + s*36;
    float a0=bb0, a1=bb1;
    #pragma unroll
    for (int i=0;i<8;i++){
      const float4 hv = *(const float4*)(row + 4*i);
      a0 = fmaf(hv.x, wa[4*i+0], a0); a0 = fmaf(hv.y, wa[4*i+1], a0);
      a0 = fmaf(hv.z, wa[4*i+2], a0); a0 = fmaf(hv.w, wa[4*i+3], a0);
      a1 = fmaf(hv.x, wb[4*i+0], a1); a1 = fmaf(hv.y, wb[4*i+1], a1);
      a1 = fmaf(hv.z, wb[4*i+2], a1); a1 = fmaf(hv.w, wb[4*i+3], a1);
    }
    s0 += a0; q0 = fmaf(a0,a0,q0); m0 = fmaxf(m0, a0);
    s1 += a1; q1 = fmaf(a1,a1,q1); m1 = fmaxf(m1, a1);
  }
  // pre-bn2 max into this block's own (now dead) x1 region: pm[pt] at x1 + pt*1024 floats
  float* pm = x1 + (size_t)(t0 + p*32)*32;
  pm[o0] = m0; pm[o1] = m1;
  // block-reduce sums -> atomics
  __syncthreads();
  h[p*64+o0] = s0; h[p*64+o1] = s1;
  h[512 + p*64+o0] = q0; h[512 + p*64+o1] = q1;
  __syncthreads();
  if (tid < 128){
    const int o = tid & 63, half = tid >> 6;
    float acc = 0.f;
    #pragma unroll
    for (int pp=0;pp<8;pp++) acc += h[half*512 + pp*64 + o];
    atomic_fx(&acc2[(blockIdx.x & 15)*128 + half*64 + o], acc);
  }
}

// ---------------- K6: bn2 + lrelu on per-point maxes, transposed write to out (B,64,N) ----------------
__global__ __launch_bounds__(256) void k_out(const float* __restrict__ x1, const float* __restrict__ bn2,
                                             float* __restrict__ out) {
  __shared__ float sm[64*65];   // [ch][pt]
  const int tid = threadIdx.x;
  const int p0 = blockIdx.x * 64;              // 64 points per block, all within one batch
  const int ptl = tid >> 2, quad = tid & 3;
  const float* src = x1 + (size_t)(p0 + ptl)*1024 + quad*16;
  #pragma unroll
  for (int k=0;k<4;k++){
    const float4 v = *(const float4*)(src + k*4);
    const int ch = quad*16 + k*4;
    sm[(ch+0)*65 + ptl] = v.x;
    sm[(ch+1)*65 + ptl] = v.y;
    sm[(ch+2)*65 + ptl] = v.z;
    sm[(ch+3)*65 + ptl] = v.w;
  }
  __syncthreads();
  const int b = p0 >> 12, n0 = p0 & (NN-1);
  #pragma unroll
  for (int i=0;i<4;i++){
    const int j = tid + i*256;
    const int ch = j >> 4, f4 = j & 15;
    const float sc = bn2[ch], sh = bn2[64+ch];
    float4 v;
    v.x = lrelu(fmaf(sm[ch*65 + f4*4+0], sc, sh));
    v.y = lrelu(fmaf(sm[ch*65 + f4*4+1], sc, sh));
    v.z = lrelu(fmaf(sm[ch*65 + f4*4+2], sc, sh));
    v.w = lrelu(fmaf(sm[ch*65 + f4*4+3], sc, sh));
    *(float4*)(out + (size_t)(b*64 + ch)*NN + n0 + f4*4) = v;
  }
}

extern "C" void kernel_launch(void* const* d_in, const int* in_sizes, int n_in,
                              void* d_out, int out_size, void* d_ws, size_t ws_size,
                              hipStream_t stream) {
  const float* pts = (const float*)d_in[0];
  const float* w0  = (const float*)d_in[1];
  const float* b0  = (const float*)d_in[2];
  const float* g0  = (const float*)d_in[3];
  const float* be0 = (const float*)d_in[4];
  const float* w1  = (const float*)d_in[5];
  const float* b1  = (const float*)d_in[6];
  const float* g1  = (const float*)d_in[7];
  const float* be1 = (const float*)d_in[8];
  const float* w2  = (const float*)d_in[9];
  const float* b2  = (const float*)d_in[10];
  const float* g2  = (const float*)d_in[11];
  const float* be2 = (const float*)d_in[12];
  float* out = (float*)d_out;

  char* ws = (char*)d_ws;
  int*       idx  = (int*)      (ws + 0);          // 2 MB
  float*     x1   = (float*)    (ws + 2097152);    // 67.1 MB -> 69206016 (pmax overlaid in-place)
  long long* acc0 = (long long*)(ws + 69206016);   // 8*27*8  (pad to 2048)
  long long* acc1 = (long long*)(ws + 69208064);   // 8*64*8  = 4096 B
  long long* acc2 = (long long*)(ws + 69212160);   // 16*128*8= 16384 B
  float*     bn0  = (float*)    (ws + 69228544);
  float*     bn1  = (float*)    (ws + 69228800);
  float*     bn2  = (float*)    (ws + 69229056);

  hipMemsetAsync((void*)acc0, 0, 22528, stream);

  k_ballquery<<<512,  256, 0, stream>>>(pts, idx);
  k_stats0g <<<512,  256, 0, stream>>>(pts, idx, acc0);
  k_fin0g   <<<1,    256, 0, stream>>>(acc0, w0, b0, g0, be0, bn0);
  k_layer01s<<<2048, 256, 0, stream>>>(pts, idx, w0, b0, bn0, w1, b1, x1, acc1);
  k_fin     <<<1,    256, 0, stream>>>(acc1, 8, 32, g1, be1, bn1);
  k_l2fused <<<2048, 256, 0, stream>>>(x1, bn1, w2, b2, acc2);
  k_fin     <<<1,    256, 0, stream>>>(acc2, 16, 64, g2, be2, bn2);
  k_out     <<<256,  256, 0, stream>>>(x1, bn2, out);
}